// Round 1
// baseline (664.841 us; speedup 1.0000x reference)
//
#include <hip/hip_runtime.h>
#include <math.h>

#define NBATCH 8
#define NFRAME 400
#define NHARM  100
#define NBAND  65
#define SRATE  16000
#define BLK    128
#define NSAMP  (NFRAME*BLK)      // 51200 samples per batch
#define IMPN   16384             // impulse padded to 64*256
#define PI_D   3.14159265358979323846

// workspace layout (byte offsets, all 16B aligned)
#define OFF_PREFIX 0             // double[8*400]        = 25600 B
#define OFF_AMPS   25600         // float[8*400*100]     = 1280000 B
#define OFF_NZ     1305600       // float[8*400*128]     = 1638400 B
#define OFF_SIG    2944000       // float[8*51200]       = 1638400 B
#define OFF_IMP    4582400       // float[16384]         = 65536 B
// total ~4.65 MB

__device__ __forceinline__ float scale_fn(float x) {
    float s = 1.0f / (1.0f + expf(-x));
    return 2.0f * powf(s, 2.3025851f) + 1e-7f;   // log(10) = 2.302585093
}

// --- exclusive prefix sum of pitch per batch (fp64), 8 serial chains ---
__global__ void k_prefix(const float* __restrict__ pitch, double* __restrict__ prefix) {
    int b = threadIdx.x;
    if (b < NBATCH) {
        double s = 0.0;
        const float* p = pitch + b * NFRAME;
        double* o = prefix + b * NFRAME;
        for (int f = 0; f < NFRAME; ++f) { o[f] = s; s += (double)p[f]; }
    }
}

// --- reverb impulse: imp[0]=1; imp[t]=rn[t]*exp(-c*t)*sigmoid(wet), zero-pad to 16384 ---
__global__ void k_imp(const float* __restrict__ rn, const float* __restrict__ decay,
                      const float* __restrict__ wet, float* __restrict__ imp) {
    int t = blockIdx.x * blockDim.x + threadIdx.x;
    if (t >= IMPN) return;
    double c  = log1p(exp(-(double)decay[0])) * (500.0 / (double)SRATE); // per-sample rate
    double wg = 1.0 / (1.0 + exp(-(double)wet[0]));
    float v;
    if (t == 0)            v = 1.0f;
    else if (t < SRATE)    v = rn[t] * (float)(exp(-c * (double)t) * wg);
    else                   v = 0.0f;
    imp[t] = v;
}

// --- per (b,f) frame: normalized harmonic amps, filtered-noise ir, nz = conv(noise, ir) ---
__global__ void k_frame(const float* __restrict__ amp_param, const float* __restrict__ noise_param,
                        const float* __restrict__ pitch, const float* __restrict__ noise,
                        float* __restrict__ amps_ws, float* __restrict__ nz_ws) {
    __shared__ float s_amps[NHARM];
    __shared__ float s_np[NBAND];
    __shared__ float s_ct[BLK];
    __shared__ float s_ir[BLK];
    __shared__ float s_noise[BLK];
    __shared__ float s_red[BLK];
    __shared__ float s_total;

    int bf = blockIdx.x;
    int tid = threadIdx.x;
    float pf = pitch[bf];

    if (tid < NHARM + 1) {
        float p = scale_fn(amp_param[bf * (NHARM + 1) + tid]);
        if (tid == 0) s_total = p;
        else {
            // aa = (pitch*k < sr/2) + 1e-4  -> 1.0001 or 0.0001, k = tid
            float aa = (pf * (float)tid < 8000.0f) ? 1.0001f : 0.0001f;
            s_amps[tid - 1] = p * aa;
        }
    }
    if (tid < NBAND) s_np[tid] = scale_fn(noise_param[bf * NBAND + tid] - 5.0f);
    s_ct[tid]    = (float)cos(2.0 * PI_D * (double)tid / 128.0);
    s_noise[tid] = noise[bf * BLK + tid];
    __syncthreads();

    // ir[n] = irfft(np)[n] * (0.5 + 0.5*cos(2*pi*n/128))  (roll/hann/roll collapsed)
    float irv;
    {
        int n = tid;
        float a = s_np[0];
        #pragma unroll
        for (int k = 1; k < NBAND - 1; ++k) a += 2.0f * s_np[k] * s_ct[(k * n) & 127];
        a += s_np[NBAND - 1] * s_ct[(64 * n) & 127];
        a *= (1.0f / 128.0f);
        a *= 0.5f + 0.5f * s_ct[n];
        irv = a;
    }

    // sum of masked amps (tree reduce over 128, entries >=100 are 0)
    s_red[tid] = (tid < NHARM) ? s_amps[tid] : 0.0f;
    __syncthreads();
    for (int s = 64; s > 0; s >>= 1) {
        if (tid < s) s_red[tid] += s_red[tid + s];
        __syncthreads();
    }
    if (tid < NHARM) {
        float v = s_amps[tid] / s_red[0] * s_total;
        amps_ws[bf * NHARM + tid] = v;
    }
    s_ir[tid] = irv;
    __syncthreads();

    // nz[p] = sum_{m<=p} noise[m] * ir[p-m]
    {
        int p = tid;
        float acc = 0.0f;
        for (int m = 0; m <= p; ++m) acc += s_noise[m] * s_ir[p - m];
        nz_ws[bf * BLK + p] = acc;
    }
}

// --- harmonic synth + add nz -> signal ---
__global__ void k_harm(const float* __restrict__ pitch, const double* __restrict__ prefix,
                       const float* __restrict__ amps_ws, const float* __restrict__ nz_ws,
                       float* __restrict__ sig) {
    __shared__ float s_amps[NHARM];
    int bf = blockIdx.x;
    int tid = threadIdx.x;
    if (tid < NHARM) s_amps[tid] = amps_ws[bf * NHARM + tid];
    __syncthreads();

    float pf = pitch[bf];
    // omega[n] (inclusive cumsum) = 2pi/sr * (128*prefix_excl + (r+1)*pitch)
    double om = (2.0 * PI_D / (double)SRATE) *
                (128.0 * prefix[bf] + (double)(tid + 1) * (double)pf);
    float th = (float)fmod(om, 2.0 * PI_D);   // exact for integer-k harmonics
    float h = 0.0f;
    #pragma unroll 4
    for (int k = 1; k <= NHARM; ++k) h += sinf(th * (float)k) * s_amps[k - 1];
    int idx = bf * BLK + tid;
    sig[idx] = h + nz_ws[idx];
}

// --- reverb: out[p] = sum_{t<=p, t<16000} imp[t]*sig[p-t] ---
#define TILE 512       // outputs per block
#define CT   256       // taps per chunk
#define KTH  128       // threads

__global__ void k_reverb(const float* __restrict__ sig, const float* __restrict__ imp,
                         float* __restrict__ out) {
    __shared__ __align__(16) float s_sig[4 + TILE + CT];  // 4-float front pad (zeros)
    __shared__ __align__(16) float s_imp[CT];

    int bid  = blockIdx.x;
    int b    = bid / (NSAMP / TILE);
    int tile = bid % (NSAMP / TILE);
    int P0   = tile * TILE;
    int tid  = threadIdx.x;
    const float* sb = sig + b * NSAMP;

    float a0 = 0.f, a1 = 0.f, a2 = 0.f, a3 = 0.f;
    int nchunks = P0 / CT + 2;                 // taps needed: t <= P0+TILE-1
    if (nchunks > 63) nchunks = 63;            // imp zero beyond 16128

    for (int c = 0; c < nchunks; ++c) {
        int T0 = c * CT;
        int W0 = P0 - T0 - CT;                 // s_sig[4+j] = sig[W0+j]
        for (int j = tid; j < TILE + CT; j += KTH) {
            int idx = W0 + j;
            s_sig[4 + j] = (idx >= 0) ? sb[idx] : 0.0f;   // idx < NSAMP guaranteed
        }
        if (tid < 4) s_sig[tid] = 0.0f;
        for (int j = tid; j < CT; j += KTH) s_imp[j] = imp[T0 + j];
        __syncthreads();

        const float4* imp4 = reinterpret_cast<const float4*>(s_imp);
        int base0 = 4 + 4 * tid + (CT - 4);    // window base for local tap 0
        float4 lo = *reinterpret_cast<const float4*>(&s_sig[base0]);
        float4 hi = *reinterpret_cast<const float4*>(&s_sig[base0 + 4]);
        #pragma unroll 8
        for (int g = 0; g < CT / 4; ++g) {
            float4 iq = imp4[g];               // wave-uniform broadcast
            // acc[o] += imp[lt+j] * sig[p+o-lt-j];  window W[x]=s_sig[base-4g+x]
            a0 += iq.x * hi.x; a0 += iq.y * lo.w; a0 += iq.z * lo.z; a0 += iq.w * lo.y;
            a1 += iq.x * hi.y; a1 += iq.y * hi.x; a1 += iq.z * lo.w; a1 += iq.w * lo.z;
            a2 += iq.x * hi.z; a2 += iq.y * hi.y; a2 += iq.z * hi.x; a2 += iq.w * lo.w;
            a3 += iq.x * hi.w; a3 += iq.y * hi.z; a3 += iq.z * hi.y; a3 += iq.w * hi.x;
            hi = lo;
            lo = *reinterpret_cast<const float4*>(&s_sig[base0 - 4 * (g + 1)]);
        }
        __syncthreads();
    }

    float4 r; r.x = a0; r.y = a1; r.z = a2; r.w = a3;
    *reinterpret_cast<float4*>(&out[b * NSAMP + P0 + 4 * tid]) = r;
}

extern "C" void kernel_launch(void* const* d_in, const int* in_sizes, int n_in,
                              void* d_out, int out_size, void* d_ws, size_t ws_size,
                              hipStream_t stream) {
    const float* amp_param   = (const float*)d_in[0];
    const float* noise_param = (const float*)d_in[1];
    const float* pitch       = (const float*)d_in[2];
    const float* noise       = (const float*)d_in[3];
    const float* rn          = (const float*)d_in[4];
    const float* decay       = (const float*)d_in[5];
    const float* wet         = (const float*)d_in[6];
    float* out = (float*)d_out;

    char* ws = (char*)d_ws;
    double* prefix = (double*)(ws + OFF_PREFIX);
    float*  amps   = (float*)(ws + OFF_AMPS);
    float*  nz     = (float*)(ws + OFF_NZ);
    float*  sig    = (float*)(ws + OFF_SIG);
    float*  imp    = (float*)(ws + OFF_IMP);

    k_prefix<<<dim3(1), dim3(64), 0, stream>>>(pitch, prefix);
    k_imp<<<dim3(IMPN / 256), dim3(256), 0, stream>>>(rn, decay, wet, imp);
    k_frame<<<dim3(NBATCH * NFRAME), dim3(128), 0, stream>>>(amp_param, noise_param, pitch, noise, amps, nz);
    k_harm<<<dim3(NBATCH * NFRAME), dim3(128), 0, stream>>>(pitch, prefix, amps, nz, sig);
    k_reverb<<<dim3(NBATCH * (NSAMP / TILE)), dim3(KTH), 0, stream>>>(sig, imp, out);
}

// Round 3
// 296.470 us; speedup vs baseline: 2.2425x; 2.2425x over previous
//
#include <hip/hip_runtime.h>
#include <math.h>

#define NBATCH 8
#define NFRAME 400
#define NHARM  100
#define NBAND  65
#define SRATE  16000
#define BLK    128
#define NSAMP  (NFRAME*BLK)      // 51200 samples per batch
#define IMPN   16384             // impulse padded to 64*256
#define PI_D   3.14159265358979323846

// workspace layout (byte offsets, all 16B aligned)
#define OFF_PREFIX 0             // double[8*400]        = 25600 B
#define OFF_AMPS   25600         // float[8*400*100]     = 1280000 B
#define OFF_NZ     1305600       // float[8*400*128]     = 1638400 B
#define OFF_SIG    2944000       // float[8*51200]       = 1638400 B
#define OFF_IMP    4582400       // float[16384]         = 65536 B
// total ~4.65 MB

__device__ __forceinline__ float scale_fn(float x) {
    float s = 1.0f / (1.0f + expf(-x));
    return 2.0f * powf(s, 2.3025851f) + 1e-7f;   // log(10) = 2.302585093
}

// --- exclusive prefix sum of pitch per batch (fp64), 8 serial chains ---
__global__ void k_prefix(const float* __restrict__ pitch, double* __restrict__ prefix) {
    int b = threadIdx.x;
    if (b < NBATCH) {
        double s = 0.0;
        const float* p = pitch + b * NFRAME;
        double* o = prefix + b * NFRAME;
        for (int f = 0; f < NFRAME; ++f) { o[f] = s; s += (double)p[f]; }
    }
}

// --- reverb impulse: imp[0]=1; imp[t]=rn[t]*exp(-c*t)*sigmoid(wet), zero-pad to 16384 ---
__global__ void k_imp(const float* __restrict__ rn, const float* __restrict__ decay,
                      const float* __restrict__ wet, float* __restrict__ imp) {
    int t = blockIdx.x * blockDim.x + threadIdx.x;
    if (t >= IMPN) return;
    double c  = log1p(exp(-(double)decay[0])) * (500.0 / (double)SRATE); // per-sample rate
    double wg = 1.0 / (1.0 + exp(-(double)wet[0]));
    float v;
    if (t == 0)            v = 1.0f;
    else if (t < SRATE)    v = rn[t] * (float)(exp(-c * (double)t) * wg);
    else                   v = 0.0f;
    imp[t] = v;
}

// --- per (b,f) frame: normalized harmonic amps, filtered-noise ir, nz = conv(noise, ir) ---
__global__ void k_frame(const float* __restrict__ amp_param, const float* __restrict__ noise_param,
                        const float* __restrict__ pitch, const float* __restrict__ noise,
                        float* __restrict__ amps_ws, float* __restrict__ nz_ws) {
    __shared__ float s_amps[NHARM];
    __shared__ float s_np[NBAND];
    __shared__ float s_ct[BLK];
    __shared__ float s_ir[BLK];
    __shared__ float s_noise[BLK];
    __shared__ float s_red[BLK];
    __shared__ float s_total;

    int bf = blockIdx.x;
    int tid = threadIdx.x;
    float pf = pitch[bf];

    if (tid < NHARM + 1) {
        float p = scale_fn(amp_param[bf * (NHARM + 1) + tid]);
        if (tid == 0) s_total = p;
        else {
            // aa = (pitch*k < sr/2) + 1e-4  -> 1.0001 or 0.0001, k = tid
            float aa = (pf * (float)tid < 8000.0f) ? 1.0001f : 0.0001f;
            s_amps[tid - 1] = p * aa;
        }
    }
    if (tid < NBAND) s_np[tid] = scale_fn(noise_param[bf * NBAND + tid] - 5.0f);
    s_ct[tid]    = (float)cos(2.0 * PI_D * (double)tid / 128.0);
    s_noise[tid] = noise[bf * BLK + tid];
    __syncthreads();

    // ir[n] = irfft(np)[n] * (0.5 + 0.5*cos(2*pi*n/128))  (roll/hann/roll collapsed)
    float irv;
    {
        int n = tid;
        float a = s_np[0];
        #pragma unroll
        for (int k = 1; k < NBAND - 1; ++k) a += 2.0f * s_np[k] * s_ct[(k * n) & 127];
        a += s_np[NBAND - 1] * s_ct[(64 * n) & 127];
        a *= (1.0f / 128.0f);
        a *= 0.5f + 0.5f * s_ct[n];
        irv = a;
    }

    // sum of masked amps (tree reduce over 128, entries >=100 are 0)
    s_red[tid] = (tid < NHARM) ? s_amps[tid] : 0.0f;
    __syncthreads();
    for (int s = 64; s > 0; s >>= 1) {
        if (tid < s) s_red[tid] += s_red[tid + s];
        __syncthreads();
    }
    if (tid < NHARM) {
        float v = s_amps[tid] / s_red[0] * s_total;
        amps_ws[bf * NHARM + tid] = v;
    }
    s_ir[tid] = irv;
    __syncthreads();

    // nz[p] = sum_{m<=p} noise[m] * ir[p-m]
    {
        int p = tid;
        float acc = 0.0f;
        for (int m = 0; m <= p; ++m) acc += s_noise[m] * s_ir[p - m];
        nz_ws[bf * BLK + p] = acc;
    }
}

// --- harmonic synth + add nz -> signal ---
__global__ void k_harm(const float* __restrict__ pitch, const double* __restrict__ prefix,
                       const float* __restrict__ amps_ws, const float* __restrict__ nz_ws,
                       float* __restrict__ sig) {
    __shared__ float s_amps[NHARM];
    int bf = blockIdx.x;
    int tid = threadIdx.x;
    if (tid < NHARM) s_amps[tid] = amps_ws[bf * NHARM + tid];
    __syncthreads();

    float pf = pitch[bf];
    // omega[n] (inclusive cumsum) = 2pi/sr * (128*prefix_excl + (r+1)*pitch)
    double om = (2.0 * PI_D / (double)SRATE) *
                (128.0 * prefix[bf] + (double)(tid + 1) * (double)pf);
    float th = (float)fmod(om, 2.0 * PI_D);   // exact for integer-k harmonics
    float h = 0.0f;
    #pragma unroll 4
    for (int k = 1; k <= NHARM; ++k) h += sinf(th * (float)k) * s_amps[k - 1];
    int idx = bf * BLK + tid;
    sig[idx] = h + nz_ws[idx];
}

// --- reverb: out[p] = sum_{t<=p, t<16000} imp[t]*sig[p-t] ---
// Tap-split parallel version: each block handles RCH chunks (of RCT taps) for one
// output tile of RTILE samples, accumulating into out via atomicAdd (out pre-zeroed).
// Per thread: 4 windows x 4 outputs = 16 accumulators -> 64 FMA per ds_read_b128 group.
#define RTILE 2048     // outputs per tile
#define RCT   256      // taps per chunk
#define RKTH  128      // threads
#define RCH   4        // chunks per block
#define RMAXSEG 16     // ceil(63 / RCH)
#define NTILES (NSAMP / RTILE)   // 25 per batch

__global__ __launch_bounds__(RKTH) void k_reverb2(const float* __restrict__ sig,
                                                  const float* __restrict__ imp,
                                                  float* __restrict__ out) {
    __shared__ __align__(16) float s_sig[4 + RTILE + RCT];  // 4-float front pad (zeros)

    int bid  = blockIdx.x;
    int seg  = bid % RMAXSEG;
    int bt   = bid / RMAXSEG;
    int b    = bt / NTILES;
    int tile = bt % NTILES;
    int P0   = tile * RTILE;
    int nch  = (P0 + RTILE) / RCT;             // taps needed: t <= P0+RTILE-1
    if (nch > 63) nch = 63;                    // imp zero beyond 16128
    int c0 = seg * RCH;
    if (c0 >= nch) return;
    int c1 = c0 + RCH; if (c1 > nch) c1 = nch;

    int tid = threadIdx.x;
    const float* sb = sig + b * NSAMP;

    float4 acc[4];
    #pragma unroll
    for (int w = 0; w < 4; ++w) { acc[w].x = 0.f; acc[w].y = 0.f; acc[w].z = 0.f; acc[w].w = 0.f; }

    int bbase = 4 + 4 * tid + (RCT - 4);       // window base (w=0) for local tap 0

    for (int c = c0; c < c1; ++c) {
        int T0 = c * RCT;
        int W0 = P0 - T0 - RCT;                // s_sig[4+j] = sig[W0+j]
        if (W0 >= 0) {
            for (int j = 4 * tid; j < RTILE + RCT; j += 4 * RKTH)
                *reinterpret_cast<float4*>(&s_sig[4 + j]) =
                    *reinterpret_cast<const float4*>(&sb[W0 + j]);
        } else {
            for (int j = tid; j < RTILE + RCT; j += RKTH) {
                int idx = W0 + j;
                s_sig[4 + j] = (idx >= 0) ? sb[idx] : 0.0f;
            }
        }
        if (tid < 4) s_sig[tid] = 0.0f;
        __syncthreads();

        const float4* imp4 = reinterpret_cast<const float4*>(imp + T0);  // block-uniform -> s_load
        float4 lo[4], hi[4];
        #pragma unroll
        for (int w = 0; w < 4; ++w) {
            lo[w] = *reinterpret_cast<const float4*>(&s_sig[bbase + 512 * w]);
            hi[w] = *reinterpret_cast<const float4*>(&s_sig[bbase + 512 * w + 4]);
        }
        #pragma unroll 4
        for (int g = 0; g < RCT / 4; ++g) {
            float4 iq = imp4[g];               // uniform: scalar-loaded, FMA from SGPR
            #pragma unroll
            for (int w = 0; w < 4; ++w) {
                acc[w].x += iq.x * hi[w].x; acc[w].x += iq.y * lo[w].w;
                acc[w].x += iq.z * lo[w].z; acc[w].x += iq.w * lo[w].y;
                acc[w].y += iq.x * hi[w].y; acc[w].y += iq.y * hi[w].x;
                acc[w].y += iq.z * lo[w].w;  acc[w].y += iq.w * lo[w].z;
                acc[w].z += iq.x * hi[w].z; acc[w].z += iq.y * hi[w].y;
                acc[w].z += iq.z * hi[w].x;  acc[w].z += iq.w * lo[w].w;
                acc[w].w += iq.x * hi[w].w; acc[w].w += iq.y * hi[w].z;
                acc[w].w += iq.z * hi[w].y;  acc[w].w += iq.w * hi[w].x;
                hi[w] = lo[w];
                lo[w] = *reinterpret_cast<const float4*>(&s_sig[bbase + 512 * w - 4 * (g + 1)]);
            }
        }
        __syncthreads();
    }

    float* ob = out + b * NSAMP + P0 + 4 * tid;
    #pragma unroll
    for (int w = 0; w < 4; ++w) {
        atomicAdd(&ob[512 * w + 0], acc[w].x);
        atomicAdd(&ob[512 * w + 1], acc[w].y);
        atomicAdd(&ob[512 * w + 2], acc[w].z);
        atomicAdd(&ob[512 * w + 3], acc[w].w);
    }
}

extern "C" void kernel_launch(void* const* d_in, const int* in_sizes, int n_in,
                              void* d_out, int out_size, void* d_ws, size_t ws_size,
                              hipStream_t stream) {
    const float* amp_param   = (const float*)d_in[0];
    const float* noise_param = (const float*)d_in[1];
    const float* pitch       = (const float*)d_in[2];
    const float* noise       = (const float*)d_in[3];
    const float* rn          = (const float*)d_in[4];
    const float* decay       = (const float*)d_in[5];
    const float* wet         = (const float*)d_in[6];
    float* out = (float*)d_out;

    char* ws = (char*)d_ws;
    double* prefix = (double*)(ws + OFF_PREFIX);
    float*  amps   = (float*)(ws + OFF_AMPS);
    float*  nz     = (float*)(ws + OFF_NZ);
    float*  sig    = (float*)(ws + OFF_SIG);
    float*  imp    = (float*)(ws + OFF_IMP);

    hipMemsetAsync(out, 0, (size_t)out_size * sizeof(float), stream);
    k_prefix<<<dim3(1), dim3(64), 0, stream>>>(pitch, prefix);
    k_imp<<<dim3(IMPN / 256), dim3(256), 0, stream>>>(rn, decay, wet, imp);
    k_frame<<<dim3(NBATCH * NFRAME), dim3(128), 0, stream>>>(amp_param, noise_param, pitch, noise, amps, nz);
    k_harm<<<dim3(NBATCH * NFRAME), dim3(128), 0, stream>>>(pitch, prefix, amps, nz, sig);
    k_reverb2<<<dim3(NBATCH * NTILES * RMAXSEG), dim3(RKTH), 0, stream>>>(sig, imp, out);
}